// Round 6
// baseline (485.196 us; speedup 1.0000x reference)
//
#include <hip/hip_runtime.h>
#include <math.h>

#define H 4096
#define E 64
#define BMROWS 16      // rows per block (1 mfma m-tile)
#define NT 256         // 4 waves; each wave owns a k-quarter
#define KQ 1024        // k per wave
#define BK 32          // floats per window (one mfma k-step after cvt)
#define NWIN (KQ / BK) // 32 windows

typedef short bf16x8 __attribute__((ext_vector_type(8)));
typedef float f32x4  __attribute__((ext_vector_type(4)));

#define GLBP(p) ((const __attribute__((address_space(1))) void*)(p))
#define LDSP(p) ((__attribute__((address_space(3))) void*)(p))

__device__ __forceinline__ unsigned f2bf_rne_u(float f) {
    unsigned u = __float_as_uint(f);
    return (u + 0x7fffu + ((u >> 16) & 1u)) >> 16;
}

// ---- kernel 1: w fp32 [64][4096] -> w_hi, w_lo bf16 (bits in ushort) ----
__global__ __launch_bounds__(256) void convert_w(const float* __restrict__ w,
                                                 unsigned short* __restrict__ wh,
                                                 unsigned short* __restrict__ wl) {
    const int i = (blockIdx.x * 256 + threadIdx.x) * 4;
    float4 v = *(const float4*)(w + i);
    float vv[4] = {v.x, v.y, v.z, v.w};
    unsigned hh[4], ll[4];
#pragma unroll
    for (int j = 0; j < 4; ++j) {
        hh[j] = f2bf_rne_u(vv[j]);
        float r = vv[j] - __uint_as_float(hh[j] << 16);
        ll[j] = __float_as_uint(r) >> 16;   // truncation: fine for residual
    }
    ushort4 h, l;
    h.x = (unsigned short)hh[0]; h.y = (unsigned short)hh[1];
    h.z = (unsigned short)hh[2]; h.w = (unsigned short)hh[3];
    l.x = (unsigned short)ll[0]; l.y = (unsigned short)ll[1];
    l.z = (unsigned short)ll[2]; l.w = (unsigned short)ll[3];
    *(ushort4*)(wh + i) = h;
    *(ushort4*)(wl + i) = l;
}

// 5-op/elem hi/lo split (numerically identical to prior rounds):
// hi = RNE-bf16(v), hi-as-float = t & 0xffff0000, lo = trunc-bf16(v - hi).
__device__ __forceinline__ void cvt8(const f32x4 a, const f32x4 b,
                                     bf16x8& hi, bf16x8& lo) {
    float v[8] = {a[0], a[1], a[2], a[3], b[0], b[1], b[2], b[3]};
#pragma unroll
    for (int i = 0; i < 8; ++i) {
        const unsigned u = __float_as_uint(v[i]);
        const unsigned t = u + 0x7fffu + ((u >> 16) & 1u); // rounded bf16 in t[31:16]
        const float    r = v[i] - __uint_as_float(t & 0xffff0000u);
        hi[i] = (short)(t >> 16);
        lo[i] = (short)(__float_as_uint(r) >> 16);
    }
}

// ---- kernel 2: fused hi/lo bf16 MFMA GEMM + top-2 + softmax ----
// R5 post-mortem fixes:
// (1) loadw issues FIRST per body, stage LAST: vmcnt is a single in-order
//     counter, so the compiler's w(k)-wait drains all older x-stages; with
//     stage-first the x prefetch collapsed to ~1-body slack. Now x-stages
//     keep >=2-body slack after every drain (covers ~900cy HBM latency).
// (2) Occupancy 2x: BMROWS=16, 32KB LDS, grid 1024 = 4 blocks/CU,
//     __launch_bounds__(256,4) -> 16 waves/CU (4/SIMD) to cover residual
//     stalls by TLP (R3 counters: occupancy 33%, all pipes <10% = latency).
// x staged global->LDS via global_load_lds (4-buffer ring, distance 3,
// wave-private, no barriers in main loop); swizzle on global src, LDS linear.
__global__ __launch_bounds__(NT, 4) void router_kernel(
    const float* __restrict__ x,
    const unsigned short* __restrict__ wh,
    const unsigned short* __restrict__ wl,
    float* __restrict__ out, int M)
{
    // 4 bufs x 4 waves x 512 floats (2 KB) = 32 KB; reused for the k-merge.
    __shared__ __align__(16) float smem[4 * 4 * 512];

    const int t    = threadIdx.x;
    const int lane = t & 63;
    const int wk   = t >> 6;        // k-quarter 0..3
    const int m0   = blockIdx.x * BMROWS;
    const int col  = lane & 15;
    const int quad = lane >> 4;     // 0..3

    // ---- staging source (pre-swizzled per-lane global addr; LDS linear) ----
    // stage call j fills rows j*8..j*8+7 of the 16x32f window; lane ->
    // (row = j*8 + lane>>3, slot-chunk = lane&7) holds global chunk
    // cg = (lane&7) ^ (row&7). 16B per lane per call; row&7 == lane>>3.
    const int srow = lane >> 3;
    const int scg  = (lane & 7) ^ srow;
    const float* gx = x + (size_t)(m0 + srow) * H + wk * KQ + scg * 4;

    // ---- read-side swizzled slot indices (f32x4 units, lane-constant) ----
    const int r7  = col & 7;
    const int sl0 = col * 8 + ((2 * quad    ) ^ r7);
    const int sl1 = col * 8 + ((2 * quad + 1) ^ r7);

    const unsigned short* whp = wh + (size_t)col * H + wk * KQ + quad * 8;
    const unsigned short* wlp = wl + (size_t)col * H + wk * KQ + quad * 8;

    f32x4 acc[4];
#pragma unroll
    for (int nt = 0; nt < 4; ++nt)
        acc[nt] = (f32x4){0.0f, 0.0f, 0.0f, 0.0f};

    uint4 wrA[8], wrB[8];   // w hi/lo ping-pong (distance 1, L2-resident)

    auto stage = [&](int win) {
        float* l = smem + ((win & 3) * 4 + wk) * 512;
        const float* g = gx + (size_t)win * BK;
#pragma unroll
        for (int j = 0; j < 2; ++j)
            __builtin_amdgcn_global_load_lds(GLBP(g + (size_t)j * 8 * H),
                                             LDSP(l + j * 256), 16, 0, 0);
    };
    auto loadw = [&](int win, uint4 (&wr)[8]) {
        const size_t k = (size_t)win * BK;
#pragma unroll
        for (int nt = 0; nt < 4; ++nt) {
            wr[nt]     = *(const uint4*)(whp + (size_t)nt * 16 * H + k);
            wr[nt + 4] = *(const uint4*)(wlp + (size_t)nt * 16 * H + k);
        }
    };
    auto compute = [&](int win, const uint4 (&wr)[8]) {
        const f32x4* sv = (const f32x4*)smem + (size_t)((win & 3) * 4 + wk) * 128;
        const f32x4 c0 = sv[sl0], c1 = sv[sl1];
        bf16x8 ah, al;
        cvt8(c0, c1, ah, al);
#pragma unroll
        for (int nt = 0; nt < 4; ++nt) {
            const bf16x8 bh = __builtin_bit_cast(bf16x8, wr[nt]);
            const bf16x8 bl = __builtin_bit_cast(bf16x8, wr[nt + 4]);
            acc[nt] = __builtin_amdgcn_mfma_f32_16x16x32_bf16(ah, bh, acc[nt], 0, 0, 0);
            acc[nt] = __builtin_amdgcn_mfma_f32_16x16x32_bf16(ah, bl, acc[nt], 0, 0, 0);
            acc[nt] = __builtin_amdgcn_mfma_f32_16x16x32_bf16(al, bh, acc[nt], 0, 0, 0);
        }
    };

    // ---- prologue: stages 0..2, then w(0). Body 0's vmcnt(22) ledger:
    // ops issued after stage(0) = s1:2 + s2:2 + w0:8 + w1:8 + s3:2 = 22 exact.
    stage(0);
    stage(1);
    stage(2);
    __builtin_amdgcn_sched_barrier(0);
    loadw(0, wrA);

    // Bodies 0..29 (15 pairs). Per body: loadw(k+1) FIRST, stage(k+3) LAST,
    // then vmcnt(22): >=22 VMEM ops are issued after stage(k) in every one of
    // these bodies, and vmcnt retires in issue order, so <=22 outstanding
    // guarantees stage(k)'s DMA landed before the ds_reads.
#pragma unroll 1
    for (int k = 0; k < NWIN - 2; k += 2) {
        // even body: compute k with wrA
        loadw(k + 1, wrB);
        stage(k + 3);                       // k+3 <= 31 always here
        asm volatile("s_waitcnt vmcnt(22)" ::: "memory");
        __builtin_amdgcn_sched_barrier(0);
        compute(k, wrA);
        // odd body: compute k+1 with wrB
        loadw(k + 2, wrA);
        if (k + 4 < NWIN) stage(k + 4);
        asm volatile("s_waitcnt vmcnt(22)" ::: "memory");
        __builtin_amdgcn_sched_barrier(0);
        compute(k + 1, wrB);
    }
    // body 30 (even, wrA loaded by body 29): issued_after(stage(30)) = 26
    loadw(31, wrB);
    asm volatile("s_waitcnt vmcnt(22)" ::: "memory");
    __builtin_amdgcn_sched_barrier(0);
    compute(30, wrA);
    // body 31: issued_after(stage(31)) = w30:8 + w31:8 = 16 -> vmcnt(8) safe
    asm volatile("s_waitcnt vmcnt(8)" ::: "memory");
    __builtin_amdgcn_sched_barrier(0);
    compute(31, wrB);

    // ---- cross-wave k-merge via LDS (staging region reused) ----
    __syncthreads();                    // all staging DMAs drained above
    f32x4* mg = (f32x4*)smem;           // [4 acc][4 wave][64 lane] = 16 KB
#pragma unroll
    for (int nt = 0; nt < 4; ++nt)
        mg[(size_t)nt * 256 + wk * 64 + lane] = acc[nt];
    __syncthreads();

    if (wk != 0) return;

    f32x4 a2[4];
#pragma unroll
    for (int nt = 0; nt < 4; ++nt) {
        f32x4 s = acc[nt];                      // own quarter (== mg[nt][0])
#pragma unroll
        for (int w = 1; w < 4; ++w)
            s += mg[(size_t)nt * 256 + w * 64 + lane];
        a2[nt] = s;
    }

    float* logits   = out;
    float* idx_out  = out + (size_t)M * E;
    float* prob_out = idx_out + (size_t)M * 2;

    const int mrow = m0 + quad * 4;
#pragma unroll
    for (int r = 0; r < 4; ++r) {
#pragma unroll
        for (int nt = 0; nt < 4; ++nt)
            logits[(size_t)(mrow + r) * E + nt * 16 + col] = a2[nt][r];

        // per-lane top-2 over its 4 experts (ascending index)
        float v1 = a2[0][r], v2 = -INFINITY;
        int   i1 = col,      i2 = 0x7fffffff;
#pragma unroll
        for (int nt = 1; nt < 4; ++nt) {
            const float v = a2[nt][r];
            const int   e = nt * 16 + col;
            if (v > v1)      { v2 = v1; i2 = i1; v1 = v; i1 = e; }
            else if (v > v2) { v2 = v;  i2 = e; }
        }
        // butterfly merge across the 16-lane row group
#pragma unroll
        for (int mask = 1; mask < 16; mask <<= 1) {
            const float ov1 = __shfl_xor(v1, mask);
            const float ov2 = __shfl_xor(v2, mask);
            const int   oi1 = __shfl_xor(i1, mask);
            const int   oi2 = __shfl_xor(i2, mask);
            const bool afirst = (v1 > ov1) || (v1 == ov1 && i1 < oi1);
            float nv1, nv2; int ni1, ni2;
            if (afirst) {
                nv1 = v1; ni1 = i1;
                const bool s = (v2 > ov1) || (v2 == ov1 && i2 < oi1);
                nv2 = s ? v2 : ov1; ni2 = s ? i2 : oi1;
            } else {
                nv1 = ov1; ni1 = oi1;
                const bool s = (ov2 > v1) || (ov2 == v1 && oi2 < i1);
                nv2 = s ? ov2 : v1; ni2 = s ? oi2 : i1;
            }
            v1 = nv1; v2 = nv2; i1 = ni1; i2 = ni2;
        }
        if (col == 0) {
            const int m = mrow + r;
            const float e2 = __expf(v2 - v1);   // <= 1
            const float d  = 1.0f + e2;
            *(float2*)(idx_out  + (size_t)m * 2) = make_float2((float)i1, (float)i2);
            *(float2*)(prob_out + (size_t)m * 2) = make_float2(1.0f / d, e2 / d);
        }
    }
}

extern "C" void kernel_launch(void* const* d_in, const int* in_sizes, int n_in,
                              void* d_out, int out_size, void* d_ws, size_t ws_size,
                              hipStream_t stream) {
    const float* x = (const float*)d_in[0];
    const float* w = (const float*)d_in[1];
    unsigned short* wh = (unsigned short*)d_ws;           // 512 KB
    unsigned short* wl = wh + (size_t)E * H;              // 512 KB
    const int M = in_sizes[0] / H;                        // 16384 rows

    hipLaunchKernelGGL(convert_w, dim3((E * H) / 1024), dim3(256), 0, stream,
                       w, wh, wl);
    hipLaunchKernelGGL(router_kernel, dim3(M / BMROWS), dim3(NT), 0, stream,
                       x, wh, wl, (float*)d_out, M);
}